// Round 10
// baseline (45.414 us; speedup 1.0000x reference)
//
#include <hip/hip_runtime.h>
#include <cstdint>

typedef unsigned long long u64;
typedef unsigned int u32;

#define BB 64
#define DD 128
#define OO 512
#define II 512             // elements (bytes in mode 0) per row
#define OT 64              // o-tile per block -> 1024 blocks

// ---------------------------------------------------------------------------
// Input-format detection. mode 0: bytes {0,1} | 1: int32 {0,1} | 2: f32 {0,1}
// Rounds 6-8 counters (cold FETCH 74MB << int32's 134MB compulsory) say the
// real data is mode 0 (bytes). Other modes kept for robustness.
// ---------------------------------------------------------------------------
__device__ __forceinline__ int detect_mode(const u32* __restrict__ w) {
    bool all01 = true, allf = true;
#pragma unroll
    for (int i = 0; i < 32; ++i) {
        u32 v = w[i];
        all01 = all01 && (v <= 1u);
        allf  = allf  && (v == 0u || v == 0x3F800000u);
    }
    return all01 ? 1 : (allf ? 2 : 0);
}

// 8 ballots pack one row's 512 bytes (lane holds bytes [8L,8L+8) as one LE
// u64) into 8 u64 words; lane j (j<8) keeps word j. Bijection (elem 8L+j ->
// word j bit L) is identical for x and w rows, so popcount(xor) is exact.
__device__ __forceinline__ u64 ballots8_bytes(u64 v, int lane) {
    u64 keep = 0;
#pragma unroll
    for (int j = 0; j < 8; ++j) {
        u64 bj = __ballot((u32)(v >> (8 * j)) & 1u);
        if (lane == j) keep = bj;
    }
    return keep;
}

// Generic global-source row packer (modes 1/2 fallback + mode 0 generic).
__device__ __forceinline__ u64 pack_row(const void* __restrict__ src,
                                        size_t elem0, int mode, int lane) {
    u64 my = 0;
    if (mode == 0) {
        u64 v = *(const u64*)((const uint8_t*)src + elem0 + (size_t)lane * 8);
        my = ballots8_bytes(v, lane);
    } else {
        const u32 sh = (mode == 1) ? 0u : 23u;   // int32: bit0; float: bit23
        const uint4* p = (const uint4*)((const u32*)src + elem0);
        uint4 a = p[lane];         // elems [4L, 4L+4)
        uint4 b = p[64 + lane];    // elems [256+4L, ...)
        u64 w0 = __ballot((a.x >> sh) & 1u), w1 = __ballot((a.y >> sh) & 1u);
        u64 w2 = __ballot((a.z >> sh) & 1u), w3 = __ballot((a.w >> sh) & 1u);
        u64 w4 = __ballot((b.x >> sh) & 1u), w5 = __ballot((b.y >> sh) & 1u);
        u64 w6 = __ballot((b.z >> sh) & 1u), w7 = __ballot((b.w >> sh) & 1u);
        if (lane == 0) my = w0;  if (lane == 1) my = w1;
        if (lane == 2) my = w2;  if (lane == 3) my = w3;
        if (lane == 4) my = w4;  if (lane == 5) my = w5;
        if (lane == 6) my = w6;  if (lane == 7) my = w7;
    }
    return my;
}

// Async global->LDS DMA, 16B/lane (1KB per wave-instr). No dest VGPR -> the
// register allocator's in-flight-load cap (rounds 6-7 wall) doesn't apply.
// Global src is per-lane (gather allowed); LDS dest = uniform base + lane*16.
__device__ __forceinline__ void gload_lds16(const void* g, void* lds) {
    __builtin_amdgcn_global_load_lds(
        (const __attribute__((address_space(1))) void*)g,
        (__attribute__((address_space(3))) void*)lds, 16, 0, 0);
}

// ---------------------------------------------------------------------------
// Single kernel. Block = (d, 64-wide o-tile); 1024 blocks; LDS 72.5KB ->
// 2 blocks/CU. XCD swizzle co-locates a d's 8 o-tiles on one XCD (per-XCD
// concurrent w-footprint = 2MB < 4MB L2, so x re-reads can now L2-hit).
// mode 0: issue ALL 64KB of DMA (32KB w-tile + 32KB x-slice) in one burst,
// ONE drain, ballot-pack both tiles from LDS, Phase C.
//   matches = 512 - popcount(x ^ w); out = (matches > bias) as int32.
// ---------------------------------------------------------------------------
__global__ __launch_bounds__(256, 2)
void binlin_one(const void* __restrict__ x, const void* __restrict__ w,
                const float* __restrict__ bias, int* __restrict__ out) {
    __shared__ u64 wstage[4096];         // 32KB raw w tile
    __shared__ u64 xstage[4096];         // 32KB raw x slice
    __shared__ u64 wp[OT][9];            // +1 pad
    __shared__ u64 xp[BB][8];            // Phase-C reads are broadcast

    const int tid  = threadIdx.x;
    const int bid  = blockIdx.x;
    const int xcd  = bid & 7;
    const int idx  = bid >> 3;           // 0..127
    const int d    = xcd * 16 + (idx >> 3);
    const int o0   = (idx & 7) * OT;
    const int wv   = tid >> 6;
    const int lane = tid & 63;

    const int mode = detect_mode((const u32*)w);
    const float bv = bias[d * OO + o0 + (tid & 63)];

    if (mode == 0) {
        const uint8_t* wtile = (const uint8_t*)w + (size_t)(d * OO + o0) * II;
        const uint8_t* xb    = (const uint8_t*)x;

        // ---- one DMA burst: 16 instrs per wave (8 w + 8 x), 64KB total ----
#pragma unroll
        for (int j = 0; j < 8; ++j) {
            const int i = wv * 8 + j;            // 0..31: 1KB chunk index
            gload_lds16(wtile + i * 1024 + lane * 16,
                        (uint8_t*)wstage + i * 1024 + lane * 16);
        }
#pragma unroll
        for (int j = 0; j < 8; ++j) {
            const int i = wv * 8 + j;            // chunk i covers b rows 2i,2i+1
            const int b = 2 * i + (lane >> 5);
            gload_lds16(xb + ((size_t)(b * DD + d)) * II + (size_t)(lane & 31) * 16,
                        (uint8_t*)xstage + i * 1024 + lane * 16);
        }
        __syncthreads();   // single drain: vmcnt(0)+lgkmcnt(0)+barrier

        // ---- ballot-pack both tiles from LDS (2-way ds_read_b64 = free) ----
#pragma unroll
        for (int r = 0; r < 16; ++r) {
            const int row = wv * 16 + r;
            u64 v = ((const u64*)wstage)[row * 64 + lane];
            u64 k = ballots8_bytes(v, lane);
            if (lane < 8) wp[row][lane] = k;
        }
#pragma unroll
        for (int r = 0; r < 16; ++r) {
            const int row = wv * 16 + r;
            u64 v = ((const u64*)xstage)[row * 64 + lane];
            u64 k = ballots8_bytes(v, lane);
            if (lane < 8) xp[row][lane] = k;
        }
        __syncthreads();
    } else {
        // Fallback (int32/f32): ballot-pack straight from global.
#pragma unroll
        for (int r = 0; r < 16; ++r) {
            const int o = wv * 16 + r;
            u64 my = pack_row(w, ((size_t)(d * OO + o0 + o)) * II, mode, lane);
            if (lane < 8) wp[o][lane] = my;
        }
#pragma unroll
        for (int r = 0; r < 16; ++r) {
            const int b = wv * 16 + r;
            u64 my = pack_row(x, ((size_t)(b * DD + d)) * II, mode, lane);
            if (lane < 8) xp[b][lane] = my;
        }
        __syncthreads();
    }

    // ---- Phase C: thread owns o = tid&63 and 16 b's ----
    const int o  = tid & 63;
    const int b0 = (tid >> 6) * 16;

    u64 wr[8];
#pragma unroll
    for (int k = 0; k < 8; ++k) wr[k] = wp[o][k];

    int* outp = out + (size_t)d * OO + o0 + o;
#pragma unroll 4
    for (int bi = 0; bi < 16; ++bi) {
        const int b = b0 + bi;
        int m = 0;
#pragma unroll
        for (int k = 0; k < 8; ++k) m += __popcll(xp[b][k] ^ wr[k]);
        const float act = (float)(512 - m);   // exact integer in fp32
        outp[(size_t)b * (DD * OO)] = (act > bv) ? 1 : 0;
    }
}

extern "C" void kernel_launch(void* const* d_in, const int* in_sizes, int n_in,
                              void* d_out, int out_size, void* d_ws, size_t ws_size,
                              hipStream_t stream) {
    const void*  x    = d_in[0];                 // (B, D, I) binary bytes
    const void*  w    = d_in[1];                 // (D, O, I) binary bytes
    const float* bias = (const float*)d_in[2];   // (D, O) f32
    int*         out  = (int*)d_out;             // (B, D, O) bool as int32

    binlin_one<<<DD * (OO / OT), 256, 0, stream>>>(x, w, bias, out);
}

// Round 11
// 44.476 us; speedup vs baseline: 1.0211x; 1.0211x over previous
//
#include <hip/hip_runtime.h>
#include <cstdint>

typedef unsigned long long u64;
typedef unsigned int u32;

#define BB 64
#define DD 128
#define OO 512
#define II 512             // elements (bytes in mode 0) per row
#define OT 64              // o-tile per block -> 1024 blocks

// ---------------------------------------------------------------------------
// Input-format detection. mode 0: bytes {0,1} | 1: int32 {0,1} | 2: f32 {0,1}
// Rounds 6-10 counters (cold FETCH 74MB << int32's 134MB compulsory) say the
// real data is mode 0 (bytes). Other modes kept for robustness.
// ---------------------------------------------------------------------------
__device__ __forceinline__ int detect_mode(const u32* __restrict__ w) {
    bool all01 = true, allf = true;
#pragma unroll
    for (int i = 0; i < 32; ++i) {
        u32 v = w[i];
        all01 = all01 && (v <= 1u);
        allf  = allf  && (v == 0u || v == 0x3F800000u);
    }
    return all01 ? 1 : (allf ? 2 : 0);
}

// 8 ballots pack one row's 512 bytes (lane holds bytes [8L,8L+8) as one LE
// u64) into 8 u64 words; lane j (j<8) keeps word j. Bijection (elem 8L+j ->
// word j bit L) is identical for x and w rows, so popcount(xor) is exact.
__device__ __forceinline__ u64 ballots8_bytes(u64 v, int lane) {
    u64 keep = 0;
#pragma unroll
    for (int j = 0; j < 8; ++j) {
        u64 bj = __ballot((u32)(v >> (8 * j)) & 1u);
        if (lane == j) keep = bj;
    }
    return keep;
}

// Generic global-source row packer (modes 1/2 fallback).
__device__ __forceinline__ u64 pack_row(const void* __restrict__ src,
                                        size_t elem0, int mode, int lane) {
    u64 my = 0;
    if (mode == 0) {
        u64 v = *(const u64*)((const uint8_t*)src + elem0 + (size_t)lane * 8);
        my = ballots8_bytes(v, lane);
    } else {
        const u32 sh = (mode == 1) ? 0u : 23u;   // int32: bit0; float: bit23
        const uint4* p = (const uint4*)((const u32*)src + elem0);
        uint4 a = p[lane];
        uint4 b = p[64 + lane];
        u64 w0 = __ballot((a.x >> sh) & 1u), w1 = __ballot((a.y >> sh) & 1u);
        u64 w2 = __ballot((a.z >> sh) & 1u), w3 = __ballot((a.w >> sh) & 1u);
        u64 w4 = __ballot((b.x >> sh) & 1u), w5 = __ballot((b.y >> sh) & 1u);
        u64 w6 = __ballot((b.z >> sh) & 1u), w7 = __ballot((b.w >> sh) & 1u);
        if (lane == 0) my = w0;  if (lane == 1) my = w1;
        if (lane == 2) my = w2;  if (lane == 3) my = w3;
        if (lane == 4) my = w4;  if (lane == 5) my = w5;
        if (lane == 6) my = w6;  if (lane == 7) my = w7;
    }
    return my;
}

// Async global->LDS DMA, 16B/lane (1KB per wave-instr). No dest VGPR, so the
// register allocator's ~8-deep in-flight cap (rounds 6-7 wall) doesn't apply.
__device__ __forceinline__ void gload_lds16(const void* g, void* lds) {
    __builtin_amdgcn_global_load_lds(
        (const __attribute__((address_space(1))) void*)g,
        (__attribute__((address_space(3))) void*)lds, 16, 0, 0);
}

// ---------------------------------------------------------------------------
// Single kernel, overlapped phases. Block = (d, 64-wide o-tile); 1024 blocks;
// LDS 41.5KB -> 3 blocks/CU. Per wave (no inter-wave sync until one barrier):
//   1) issue 8 w-DMA instrs (its 16 rows, 16KB in flight, VGPR-free)
//   2) ballot-pack its 16 x rows from GLOBAL (L3-hot) -> xp   [covers DMA]
//   3) vmcnt(0); ballot-pack its 16 w rows from LDS -> wp
//   4) one __syncthreads; Phase C (thread owns o=tid&63, its wave's 16 b's):
//      matches = 512 - popcount(x ^ w); out = (matches > bias) as int32.
// XCD swizzle co-locates each d's 8 o-tiles on one XCD for x L2/L3 reuse.
// ---------------------------------------------------------------------------
__global__ __launch_bounds__(256, 3)
void binlin_one(const void* __restrict__ x, const void* __restrict__ w,
                const float* __restrict__ bias, int* __restrict__ out) {
    __shared__ u64 wstage[4096];         // 32KB raw w tile
    __shared__ u64 wp[OT][9];            // +1 pad: Phase-C read <=4-way
    __shared__ u64 xp[BB][8];            // Phase-C reads are broadcast

    const int tid  = threadIdx.x;
    const int bid  = blockIdx.x;
    const int xcd  = bid & 7;
    const int idx  = bid >> 3;           // 0..127
    const int d    = xcd * 16 + (idx >> 3);
    const int o0   = (idx & 7) * OT;
    const int wv   = tid >> 6;
    const int lane = tid & 63;

    const int mode = detect_mode((const u32*)w);
    const float bv = bias[d * OO + o0 + (tid & 63)];   // early: latency hides

    if (mode == 0) {
        const uint8_t* wtile = (const uint8_t*)w + (size_t)(d * OO + o0) * II;
        const uint8_t* xb    = (const uint8_t*)x;

        // ---- 1) w-DMA burst: 8 instrs, wave's own rows 16wv..16wv+15 ----
#pragma unroll
        for (int j = 0; j < 8; ++j) {
            const int i = wv * 8 + j;            // 1KB chunk = rows 2i,2i+1
            gload_lds16(wtile + i * 1024 + lane * 16,
                        (uint8_t*)wstage + i * 1024 + lane * 16);
        }
        // ---- 2) x ballot-pack from global (overlaps the DMA flight) ----
#pragma unroll
        for (int r = 0; r < 16; ++r) {
            const int b = wv * 16 + r;
            u64 v = *(const u64*)(xb + ((size_t)(b * DD + d)) * II
                                     + (size_t)lane * 8);
            u64 k = ballots8_bytes(v, lane);
            if (lane < 8) xp[b][lane] = k;
        }
        // ---- 3) drain own DMAs, pack own w rows from LDS ----
        asm volatile("s_waitcnt vmcnt(0)" ::: "memory");
        __builtin_amdgcn_sched_barrier(0);
#pragma unroll
        for (int r = 0; r < 16; ++r) {
            const int row = wv * 16 + r;
            u64 v = ((const u64*)wstage)[row * 64 + lane];
            u64 k = ballots8_bytes(v, lane);
            if (lane < 8) wp[row][lane] = k;
        }
    } else {
        // Fallback (int32/f32): ballot-pack straight from global.
#pragma unroll
        for (int r = 0; r < 16; ++r) {
            const int o = wv * 16 + r;
            u64 my = pack_row(w, ((size_t)(d * OO + o0 + o)) * II, mode, lane);
            if (lane < 8) wp[o][lane] = my;
        }
#pragma unroll
        for (int r = 0; r < 16; ++r) {
            const int b = wv * 16 + r;
            u64 my = pack_row(x, ((size_t)(b * DD + d)) * II, mode, lane);
            if (lane < 8) xp[b][lane] = my;
        }
    }
    __syncthreads();

    // ---- Phase C: thread owns o = tid&63 and its wave's 16 b's ----
    const int o  = tid & 63;
    const int b0 = (tid >> 6) * 16;

    u64 wr[8];
#pragma unroll
    for (int k = 0; k < 8; ++k) wr[k] = wp[o][k];

    int* outp = out + (size_t)d * OO + o0 + o;
#pragma unroll 4
    for (int bi = 0; bi < 16; ++bi) {
        const int b = b0 + bi;
        int m = 0;
#pragma unroll
        for (int k = 0; k < 8; ++k) m += __popcll(xp[b][k] ^ wr[k]);
        const float act = (float)(512 - m);   // exact integer in fp32
        outp[(size_t)b * (DD * OO)] = (act > bv) ? 1 : 0;
    }
}

extern "C" void kernel_launch(void* const* d_in, const int* in_sizes, int n_in,
                              void* d_out, int out_size, void* d_ws, size_t ws_size,
                              hipStream_t stream) {
    const void*  x    = d_in[0];                 // (B, D, I) binary bytes
    const void*  w    = d_in[1];                 // (D, O, I) binary bytes
    const float* bias = (const float*)d_in[2];   // (D, O) f32
    int*         out  = (int*)d_out;             // (B, D, O) bool as int32

    binlin_one<<<DD * (OO / OT), 256, 0, stream>>>(x, w, bias, out);
}

// Round 12
// 38.957 us; speedup vs baseline: 1.1658x; 1.1417x over previous
//
#include <hip/hip_runtime.h>
#include <cstdint>

typedef unsigned long long u64;
typedef unsigned int u32;

#define BB 64
#define DD 128
#define OO 512
#define II 512             // elements (bytes in mode 0) per row
#define OT 64              // o-tile per block -> 1024 blocks
#define LROW 72            // LDS row stride in bytes (9 u64: pad for Phase C)

// ---------------------------------------------------------------------------
// Input-format detection. mode 0: bytes {0,1} | 1: int32 {0,1} | 2: f32 {0,1}
// Rounds 6-10 counters (cold FETCH 74MB << int32's 134MB compulsory) say the
// real data is mode 0 (bytes). Other modes kept for robustness.
// ---------------------------------------------------------------------------
__device__ __forceinline__ int detect_mode(const u32* __restrict__ w) {
    bool all01 = true, allf = true;
#pragma unroll
    for (int i = 0; i < 32; ++i) {
        u32 v = w[i];
        all01 = all01 && (v <= 1u);
        allf  = allf  && (v == 0u || v == 0x3F800000u);
    }
    return all01 ? 1 : (allf ? 2 : 0);
}

// Multiply trick (R2-verified): u32 with 4 bytes in {0,1} -> 4 bits, bit m =
// byte m's LSB. Contributions land on bits 24..27, no carries.
__device__ __forceinline__ u32 nib4(u32 v) {
    return ((v * 0x01020408u) >> 24) & 0xFu;
}
// u64 holding 8 bytes {0,1} -> 8-bit pack. NO cross-lane ops (the round-11
// diagnosis: __ballot is convergent and blocks load pipelining).
__device__ __forceinline__ u32 byte8(u64 v) {
    return nib4((u32)v) | (nib4((u32)(v >> 32)) << 4);
}

// Ballot-based row packer, kept ONLY for the mode 1/2 fallback.
__device__ __forceinline__ u64 pack_row_ballot(const void* __restrict__ src,
                                               size_t elem0, int mode, int lane) {
    const u32 sh = (mode == 1) ? 0u : 23u;
    const uint4* p = (const uint4*)((const u32*)src + elem0);
    uint4 a = p[lane];
    uint4 b = p[64 + lane];
    u64 w0 = __ballot((a.x >> sh) & 1u), w1 = __ballot((a.y >> sh) & 1u);
    u64 w2 = __ballot((a.z >> sh) & 1u), w3 = __ballot((a.w >> sh) & 1u);
    u64 w4 = __ballot((b.x >> sh) & 1u), w5 = __ballot((b.y >> sh) & 1u);
    u64 w6 = __ballot((b.z >> sh) & 1u), w7 = __ballot((b.w >> sh) & 1u);
    u64 my = 0;
    if (lane == 0) my = w0;  if (lane == 1) my = w1;
    if (lane == 2) my = w2;  if (lane == 3) my = w3;
    if (lane == 4) my = w4;  if (lane == 5) my = w5;
    if (lane == 6) my = w6;  if (lane == 7) my = w7;
    return my;
}

// ---------------------------------------------------------------------------
// Single kernel (R7 structure, convergence-free pack). Block = (d, 64-wide
// o-tile); 1024 blocks; LDS ~9.2KB -> 4 blocks/CU by launch_bounds.
// Pack: per wave, 32 independent 8B/lane coalesced row-loads (16 w + 16 x),
// then per-lane byte8 + ds_write_u8 (byte L of packed row = source bytes
// [8L,8L+8) LSBs; bijection identical for x and w -> popcount(xor) exact).
// Phase C: thread owns o = tid&63 and 16 b's:
//   matches = 512 - popcount(x ^ w); out = (matches > bias) as int32.
// ---------------------------------------------------------------------------
__global__ __launch_bounds__(256, 4)
void binlin_one(const void* __restrict__ x, const void* __restrict__ w,
                const float* __restrict__ bias, int* __restrict__ out) {
    __shared__ u64 wp[OT][9];            // stride 72B; Phase-C read <=4-way
    __shared__ u64 xp[BB][9];            // Phase-C reads are broadcast

    const int tid  = threadIdx.x;
    const int bid  = blockIdx.x;
    const int xcd  = bid & 7;
    const int idx  = bid >> 3;           // 0..127
    const int d    = xcd * 16 + (idx >> 3);
    const int o0   = (idx & 7) * OT;
    const int wv   = tid >> 6;
    const int lane = tid & 63;

    const int mode = detect_mode((const u32*)w);
    const float bv = bias[d * OO + o0 + (tid & 63)];

    uint8_t* wpb = (uint8_t*)wp;
    uint8_t* xpb = (uint8_t*)xp;

    if (mode == 0) {
        const uint8_t* wt = (const uint8_t*)w + (size_t)(d * OO + o0) * II;
        const uint8_t* xb = (const uint8_t*)x;

        u64 vw[16], vx[16];
        // 32 independent coalesced loads, no convergent ops anywhere near:
        // the scheduler can keep them all in flight.
#pragma unroll
        for (int r = 0; r < 16; ++r)
            vw[r] = *(const u64*)(wt + (size_t)(wv * 16 + r) * II
                                     + (size_t)lane * 8);
#pragma unroll
        for (int r = 0; r < 16; ++r)
            vx[r] = *(const u64*)(xb + ((size_t)((wv * 16 + r) * DD + d)) * II
                                     + (size_t)lane * 8);
        // pure per-lane pack + byte store (4-way LDS write, ~free)
#pragma unroll
        for (int r = 0; r < 16; ++r)
            wpb[(wv * 16 + r) * LROW + lane] = (uint8_t)byte8(vw[r]);
#pragma unroll
        for (int r = 0; r < 16; ++r)
            xpb[(wv * 16 + r) * LROW + lane] = (uint8_t)byte8(vx[r]);
    } else {
        // Fallback (int32/f32 data): ballot pack straight from global.
#pragma unroll
        for (int r = 0; r < 16; ++r) {
            const int o = wv * 16 + r;
            u64 my = pack_row_ballot(w, ((size_t)(d * OO + o0 + o)) * II, mode, lane);
            if (lane < 8) wp[o][lane] = my;
        }
#pragma unroll
        for (int r = 0; r < 16; ++r) {
            const int b = wv * 16 + r;
            u64 my = pack_row_ballot(x, ((size_t)(b * DD + d)) * II, mode, lane);
            if (lane < 8) xp[b][lane] = my;
        }
    }
    __syncthreads();

    // ---- Phase C: thread owns o = tid&63 and its wave's 16 b's ----
    const int o  = tid & 63;
    const int b0 = (tid >> 6) * 16;

    u64 wr[8];
#pragma unroll
    for (int k = 0; k < 8; ++k) wr[k] = wp[o][k];

    int* outp = out + (size_t)d * OO + o0 + o;
#pragma unroll 4
    for (int bi = 0; bi < 16; ++bi) {
        const int b = b0 + bi;
        int m = 0;
#pragma unroll
        for (int k = 0; k < 8; ++k) m += __popcll(xp[b][k] ^ wr[k]);
        const float act = (float)(512 - m);   // exact integer in fp32
        outp[(size_t)b * (DD * OO)] = (act > bv) ? 1 : 0;
    }
}

extern "C" void kernel_launch(void* const* d_in, const int* in_sizes, int n_in,
                              void* d_out, int out_size, void* d_ws, size_t ws_size,
                              hipStream_t stream) {
    const void*  x    = d_in[0];                 // (B, D, I) binary bytes
    const void*  w    = d_in[1];                 // (D, O, I) binary bytes
    const float* bias = (const float*)d_in[2];   // (D, O) f32
    int*         out  = (int*)d_out;             // (B, D, O) bool as int32

    binlin_one<<<DD * (OO / OT), 256, 0, stream>>>(x, w, bias, out);
}

// Round 13
// 37.024 us; speedup vs baseline: 1.2266x; 1.0522x over previous
//
#include <hip/hip_runtime.h>
#include <cstdint>

typedef unsigned long long u64;
typedef unsigned int u32;

#define BB 64
#define DD 128
#define OO 512
#define II 512             // elements (bytes in mode 0) per row
#define SOT 32             // o-subtile (pipeline stage)
#define NSUB 4             // subtiles per block
#define BOT (SOT * NSUB)   // 128 o per block -> 512 blocks

// ---------------------------------------------------------------------------
// Input-format detection. mode 0: bytes {0,1} | 1: int32 {0,1} | 2: f32 {0,1}
// Rounds 6-12 counters (cold FETCH 74MB << int32's 134MB compulsory) say the
// real data is mode 0 (bytes). Other modes kept for robustness.
// ---------------------------------------------------------------------------
__device__ __forceinline__ int detect_mode(const u32* __restrict__ w) {
    bool all01 = true, allf = true;
#pragma unroll
    for (int i = 0; i < 32; ++i) {
        u32 v = w[i];
        all01 = all01 && (v <= 1u);
        allf  = allf  && (v == 0u || v == 0x3F800000u);
    }
    return all01 ? 1 : (allf ? 2 : 0);
}

// Multiply trick: u32 with 4 bytes in {0,1} -> 4 bits (bit m = byte m LSB).
__device__ __forceinline__ u32 nib4(u32 v) {
    return ((v * 0x01020408u) >> 24) & 0xFu;
}
// u64 of 8 bytes {0,1} -> 8 bits. Pure per-lane; byte L of a packed row =
// source bytes [8L,8L+8). Bijection identical for x and w -> popcount exact.
__device__ __forceinline__ u32 byte8(u64 v) {
    return nib4((u32)v) | (nib4((u32)(v >> 32)) << 4);
}

// Ballot row packer for the mode 1/2 fallback (lane j<8 keeps word j).
__device__ __forceinline__ u64 pack_row_ballot(const void* __restrict__ src,
                                               size_t elem0, int mode, int lane) {
    const u32 sh = (mode == 1) ? 0u : 23u;
    const uint4* p = (const uint4*)((const u32*)src + elem0);
    uint4 a = p[lane];
    uint4 b = p[64 + lane];
    u64 w0 = __ballot((a.x >> sh) & 1u), w1 = __ballot((a.y >> sh) & 1u);
    u64 w2 = __ballot((a.z >> sh) & 1u), w3 = __ballot((a.w >> sh) & 1u);
    u64 w4 = __ballot((b.x >> sh) & 1u), w5 = __ballot((b.y >> sh) & 1u);
    u64 w6 = __ballot((b.z >> sh) & 1u), w7 = __ballot((b.w >> sh) & 1u);
    u64 my = 0;
    if (lane == 0) my = w0;  if (lane == 1) my = w1;
    if (lane == 2) my = w2;  if (lane == 3) my = w3;
    if (lane == 4) my = w4;  if (lane == 5) my = w5;
    if (lane == 6) my = w6;  if (lane == 7) my = w7;
    return my;
}

// ---------------------------------------------------------------------------
// Pipelined kernel. Block = (d, 128-wide o-range); 512 blocks; LDS 9.2KB.
// Prologue: issue subtile-0 w loads; pack x slice (16 rows/wave) while they
// fly. Loop s=0..3: issue s+1's loads -> Phase C(s) (the overlap work all
// previous rounds lacked) -> pack s+1 into the other wp buffer -> barrier.
// Phase C: thread owns o = tid&31 of the subtile and 8 b's:
//   matches = 512 - popcount(x ^ w); out = (matches > bias) as int32.
// ---------------------------------------------------------------------------
__device__ __forceinline__ void phase_c(const u64 (*__restrict__ wpb)[9],
                                        const u64 (*__restrict__ xp)[9],
                                        const float* __restrict__ bias,
                                        int* __restrict__ out,
                                        int d, int ocol, int tid) {
    const int ol = tid & 31;             // o within subtile
    const int b0 = (tid >> 5) * 8;
    const float bv = bias[d * OO + ocol + ol];
    u64 wr[8];
#pragma unroll
    for (int k = 0; k < 8; ++k) wr[k] = wpb[ol][k];
    int* outp = out + (size_t)d * OO + ocol + ol;
#pragma unroll
    for (int bi = 0; bi < 8; ++bi) {
        const int b = b0 + bi;
        int m = 0;
#pragma unroll
        for (int k = 0; k < 8; ++k) m += __popcll(xp[b][k] ^ wr[k]);
        const float act = (float)(512 - m);   // exact integer in fp32
        outp[(size_t)b * (DD * OO)] = (act > bv) ? 1 : 0;
    }
}

__global__ __launch_bounds__(256, 2)
void binlin_pipe(const void* __restrict__ x, const void* __restrict__ w,
                 const float* __restrict__ bias, int* __restrict__ out) {
    __shared__ u64 xp[BB][9];            // packed x slice (stride 72B)
    __shared__ u64 wp[2][SOT][9];        // double-buffered packed w subtile

    const int tid  = threadIdx.x;
    const int bid  = blockIdx.x;
    const int xcd  = bid & 7;
    const int idx  = bid >> 3;           // 0..63
    const int d    = xcd * 16 + (idx >> 2);
    const int ob   = (idx & 3) * BOT;    // o-range base
    const int wv   = tid >> 6;
    const int lane = tid & 63;

    const int mode = detect_mode((const u32*)w);

    if (mode == 0) {
        const uint8_t* wt = (const uint8_t*)w + ((size_t)d * OO + ob) * II;
        const uint8_t* xb = (const uint8_t*)x;

        // ---- prologue: issue subtile-0 w loads ----
        u64 vw[8];
#pragma unroll
        for (int r = 0; r < 8; ++r)
            vw[r] = *(const u64*)(wt + (size_t)(wv * 8 + r) * II
                                     + (size_t)lane * 8);
        __builtin_amdgcn_sched_barrier(0);

        // ---- pack x slice while subtile-0 flies (16 rows/wave) ----
        u64 vx[16];
#pragma unroll
        for (int r = 0; r < 16; ++r)
            vx[r] = *(const u64*)(xb + ((size_t)((wv * 16 + r) * DD + d)) * II
                                     + (size_t)lane * 8);
#pragma unroll
        for (int r = 0; r < 16; ++r)
            ((uint8_t*)xp)[(wv * 16 + r) * 72 + lane] = (uint8_t)byte8(vx[r]);

        // ---- pack subtile 0 ----
#pragma unroll
        for (int r = 0; r < 8; ++r)
            ((uint8_t*)wp[0])[(wv * 8 + r) * 72 + lane] = (uint8_t)byte8(vw[r]);
        __syncthreads();

        // ---- pipelined subtile loop ----
#pragma unroll
        for (int s = 0; s < NSUB; ++s) {
            u64 vn[8];
            if (s + 1 < NSUB) {          // issue next subtile's loads NOW
#pragma unroll
                for (int r = 0; r < 8; ++r)
                    vn[r] = *(const u64*)(wt + (size_t)((s + 1) * SOT + wv * 8 + r) * II
                                             + (size_t)lane * 8);
                __builtin_amdgcn_sched_barrier(0);
            }
            // Phase C on current subtile: covers the in-flight loads
            phase_c(wp[s & 1], xp, bias, out, d, ob + s * SOT, tid);
            if (s + 1 < NSUB) {          // pack next into the other buffer
#pragma unroll
                for (int r = 0; r < 8; ++r)
                    ((uint8_t*)wp[(s + 1) & 1])[(wv * 8 + r) * 72 + lane] =
                        (uint8_t)byte8(vn[r]);
                __syncthreads();
            }
        }
    } else {
        // ---- fallback (int32/f32): non-pipelined ballot path ----
#pragma unroll
        for (int r = 0; r < 16; ++r) {
            const int b = wv * 16 + r;
            u64 my = pack_row_ballot(x, ((size_t)(b * DD + d)) * II, mode, lane);
            if (lane < 8) xp[b][lane] = my;
        }
        for (int s = 0; s < NSUB; ++s) {
#pragma unroll
            for (int r = 0; r < 8; ++r) {
                const int o = ob + s * SOT + wv * 8 + r;
                u64 my = pack_row_ballot(w, ((size_t)(d * OO + o)) * II, mode, lane);
                if (lane < 8) wp[s & 1][wv * 8 + r][lane] = my;
            }
            __syncthreads();
            phase_c(wp[s & 1], xp, bias, out, d, ob + s * SOT, tid);
            __syncthreads();
        }
    }
}

extern "C" void kernel_launch(void* const* d_in, const int* in_sizes, int n_in,
                              void* d_out, int out_size, void* d_ws, size_t ws_size,
                              hipStream_t stream) {
    const void*  x    = d_in[0];                 // (B, D, I) binary bytes
    const void*  w    = d_in[1];                 // (D, O, I) binary bytes
    const float* bias = (const float*)d_in[2];   // (D, O) f32
    int*         out  = (int*)d_out;             // (B, D, O) bool as int32

    binlin_pipe<<<DD * (OO / BOT), 256, 0, stream>>>(x, w, bias, out);
}